// Round 8
// baseline (98.184 us; speedup 1.0000x reference)
//
#include <hip/hip_runtime.h>
#include <cmath>

#define DEVFN __device__ __forceinline__

constexpr int Bn = 4096, Dn = 1024, An = 64, Tn = 16;
constexpr int CAP = 512;     // per-task row capacity (mean 256, +16.5 sigma)

// ---------------- workspace layout (bytes) ----------------
constexpr size_t OFF_CURSOR = 0;                                 // Tn ints
constexpr size_t OFF_BUCKET = 256;                               // Tn*CAP ints = 32KB
constexpr size_t OFF_FEATB  = 33024;                             // bf16 [Bn][Dn] = 8MB
constexpr size_t OFF_W1T    = OFF_FEATB + (size_t)2 * Bn * Dn;   // bf16 [Tn][n][k] = 32MB
constexpr size_t OFF_H      = OFF_W1T + (size_t)2 * Tn * Dn * Dn;// bf16 [Tn*CAP][Dn] = 16MB
constexpr size_t WS_NEED    = OFF_H + (size_t)2 * Tn * CAP * Dn; // ~56.1MB

typedef unsigned short u16;
typedef unsigned int uint32;
typedef __bf16 bf16x8 __attribute__((ext_vector_type(8)));
typedef float f32x4 __attribute__((ext_vector_type(4)));

DEVFN u16 f2b(float x) {            // f32 -> bf16 RNE
    unsigned u = __float_as_uint(x);
    u = u + 0x7FFFu + ((u >> 16) & 1u);
    return (u16)(u >> 16);
}
DEVFN uint32 pk2(float lo, float hi) {   // packed f32x2 -> bf16x2 (RNE)
    uint32 r;
    asm("v_cvt_pk_bf16_f32 %0, %1, %2" : "=v"(r) : "v"(lo), "v"(hi));
    return r;
}
DEVFN void gload_lds16(const void* g, void* l) {
    __builtin_amdgcn_global_load_lds(
        (const __attribute__((address_space(1))) void*)g,
        (__attribute__((address_space(3))) void*)l, 16, 0, 0);
}

// ------- prep: feature cvt + W1 transpose-cvt (r0 verified) + zero-fills -----
__global__ __launch_bounds__(256) void k_prep(
    const float* __restrict__ feat, const float* __restrict__ w1,
    u16* __restrict__ featb, u16* __restrict__ w1t,
    int* __restrict__ cursor, int* __restrict__ bucket) {
    __shared__ float tile[64][65];
    const int bid = blockIdx.x, tid = threadIdx.x;
    if (bid == 0) {
        if (tid < Tn) cursor[tid] = 0;
        int4* bz = (int4*)bucket; int4 z = {0, 0, 0, 0};
        #pragma unroll
        for (int i = 0; i < 8; ++i) bz[tid * 8 + i] = z;   // Tn*CAP ints
    }
    if (bid < 1024) {
        const float4* s = (const float4*)feat;
        ushort4* d = (ushort4*)featb;
        const int base = bid * 1024 + tid;
        #pragma unroll
        for (int i = 0; i < 4; ++i) {
            float4 v = s[base + i * 256];
            ushort4 o = {f2b(v.x), f2b(v.y), f2b(v.z), f2b(v.w)};
            d[base + i * 256] = o;
        }
    } else {
        const int tb = bid - 1024;            // 0..4095
        const int t = tb >> 8;
        const int rest = tb & 255;
        const int k0 = (rest & 15) * 64, n0 = (rest >> 4) * 64;
        const float* s = w1 + ((size_t)t * Dn + k0) * Dn + n0;
        #pragma unroll
        for (int i = 0; i < 4; ++i) {
            const int row = i * 16 + (tid >> 4);
            const int c = (tid & 15) * 4;
            float4 v = *(const float4*)&s[(size_t)row * Dn + c];
            tile[row][c] = v.x; tile[row][c + 1] = v.y;
            tile[row][c + 2] = v.z; tile[row][c + 3] = v.w;
        }
        __syncthreads();
        u16* d = w1t + ((size_t)t * Dn + n0) * Dn + k0;
        #pragma unroll
        for (int i = 0; i < 2; ++i) {
            const int chunk = i * 256 + tid;
            const int nr = chunk >> 3, kc = chunk & 7;
            float v[8];
            #pragma unroll
            for (int u = 0; u < 8; ++u) v[u] = tile[kc * 8 + u][nr];
            uint4 w = {pk2(v[0], v[1]), pk2(v[2], v[3]), pk2(v[4], v[5]), pk2(v[6], v[7])};
            *(uint4*)&d[(size_t)nr * Dn + kc * 8] = w;
        }
    }
}

// ---------------- scatter: argmax + bucket append (CAP segments) -------------
__global__ void k_scatter(const float* __restrict__ ai, int* __restrict__ cursor,
                          int* __restrict__ bucket) {
    int b = blockIdx.x * 256 + threadIdx.x;
    if (b >= Bn) return;
    const float4* r = (const float4*)(ai + (size_t)b * Tn);
    float4 v0 = r[0], v1 = r[1], v2 = r[2], v3 = r[3];
    float vals[16] = {v0.x, v0.y, v0.z, v0.w, v1.x, v1.y, v1.z, v1.w,
                      v2.x, v2.y, v2.z, v2.w, v3.x, v3.y, v3.z, v3.w};
    float best = vals[0]; int bi = 0;
    #pragma unroll
    for (int i = 1; i < Tn; ++i) if (vals[i] > best) { best = vals[i]; bi = i; }
    int pos = atomicAdd(&cursor[bi], 1);
    if (pos < CAP) bucket[bi * CAP + pos] = b;
}

// ---------------- gemm1 v8: B-ONCE, all-mt-inline, DMA-only staging ----------
// r1-r7 invariant: ~196MB demand at ~4.5TB/s L2-miss tier = ~42us regardless
// of schedule. This kernel removes the duplicated bytes:
//   block = (t, 64-col slab); grid 16x16=256 (1/CU, co-resident). Each block
//   loops ALL mt sub-tiles inline -> W1T read ONCE (32MB bf16 total). The 16
//   same-t slab siblings share one XCD (t=bid&15) in lockstep -> featb unique
//   ~1MB/XCD, L2-served. L2-miss demand ~48MB (vs 196).
// All staging = global_load_lds (no register consumers) -> uniform counted
// waits: every body issues exactly 6 DMAs (A-next2: 4, B(ks+2): 2; B dup-
// staged per body of the same ks -- benign identical writes). 3-deep LDS
// buffers for A and B (distance-2). At each body: outstanding =
// stage(s-1)+stage(s) = 12 -> vmcnt(12) retires stage(s-2) = exactly this
// body's A-tile + B-tile; barrier makes it block-wide. No pk2/register-B ->
// the r5 hoist-past-waitcnt hazard is structurally impossible.
// acc[4 mt][4][2] statically indexed (rule #20); mt guards wave-uniform.
__global__ __launch_bounds__(256, 1) void k_gemm1(
    const u16* __restrict__ featb, const u16* __restrict__ w1t,
    const float* __restrict__ b1, const int* __restrict__ bucket,
    const int* __restrict__ cursor, u16* __restrict__ hbuf) {
    __shared__ __align__(16) u16 As[3][128 * 64];   // 16KB x3
    __shared__ __align__(16) u16 Bs[3][64 * 64];    // 8KB x3 (72KB total)

    const int bid = blockIdx.x;
    const int t = bid & 15, sl = bid >> 4;          // slab 0..15
    const int n0 = sl * 64;
    const int tid = threadIdx.x, lane = tid & 63, wv = tid >> 6;
    const int wr = wv >> 1, wc = wv & 1;            // 2x2 waves, tile 64x32

    // row byte-offsets for all 4 mt tiles (bucket zero-filled -> in-bounds)
    const int kca = tid & 7;
    int rowOff[4][4];
    #pragma unroll
    for (int mt = 0; mt < 4; ++mt)
        #pragma unroll
        for (int i = 0; i < 4; ++i) {
            const int r = i * 32 + (tid >> 3);
            const int ri = bucket[t * CAP + mt * 128 + r];
            rowOff[mt][i] = ri * (Dn * 2) + 16 * (kca ^ (r & 7));
        }
    int cnt = cursor[t]; if (cnt > CAP) cnt = CAP;
    if (cnt == 0) return;
    const bool L1 = cnt > 128, L2v = cnt > 256, L3v = cnt > 384;

    const char* featB = (const char*)featb;
    const u16* wbase = w1t + ((size_t)t * Dn + n0) * Dn;

    auto stageA = [&](const int (&ro)[4], int ksv, int slot) {
        #pragma unroll
        for (int i = 0; i < 4; ++i)
            gload_lds16(featB + ro[i] + ksv * 128, &As[slot][(i * 256 + tid) * 8]);
    };
    auto stageB = [&](int ksv, int slot) {
        #pragma unroll
        for (int j = 0; j < 2; ++j) {
            const int g = j * 256 + tid;
            const int n = g >> 3, kb = g & 7;
            gload_lds16(wbase + (size_t)n * Dn + ksv * 64 + 8 * (kb ^ (n & 7)),
                        &Bs[slot][g * 8]);
        }
    };

    f32x4 acc[4][4][2] = {};                        // [mt][i][j], static idx
    auto compute = [&](f32x4 (&am)[4][2], int sa_, int sb_) {
        #pragma unroll
        for (int h = 0; h < 2; ++h) {
            const int kq = h * 4 + (lane >> 4);
            bf16x8 af[4], bfr[2];
            #pragma unroll
            for (int i = 0; i < 4; ++i) {
                int rr = wr * 64 + i * 16 + (lane & 15);
                af[i] = *(const bf16x8*)&As[sa_][rr * 64 + 8 * (kq ^ (rr & 7))];
            }
            #pragma unroll
            for (int j = 0; j < 2; ++j) {
                int nn = wc * 32 + j * 16 + (lane & 15);
                bfr[j] = *(const bf16x8*)&Bs[sb_][nn * 64 + 8 * (kq ^ (nn & 7))];
            }
            #pragma unroll
            for (int i = 0; i < 4; ++i)
                #pragma unroll
                for (int j = 0; j < 2; ++j)
                    am[i][j] = __builtin_amdgcn_mfma_f32_16x16x32_bf16(af[i], bfr[j], am[i][j], 0, 0, 0);
        }
    };

    // drain bucket/cursor loads so the DMA queue arithmetic starts at 0
    asm volatile("s_waitcnt vmcnt(0)" ::: "memory");
    // prologue: stage(-2) = {A(flat0)=tile(0,ks0), B(0)}; stage(-1) = {A(flat1), B(1)}
    stageA(rowOff[0], 0, 0); stageB(0, 0);
    if (L1) stageA(rowOff[1], 0, 1); else stageA(rowOff[0], 1, 1);
    stageB(1, 1);

    int sa = 0, sb = 0;
    #pragma unroll 1
    for (int ks = 0; ks < 16; ++ks) {
        int sb2 = sb + 2; if (sb2 >= 3) sb2 -= 3;
        const int kc2 = ks + 2 < 16 ? ks + 2 : 15;
        const int kn  = ks + 1 < 16 ? ks + 1 : 15;
        {   // body (ks, 0): next2 = L2v?(ks,2) : L1?(ks+1,0) : (ks+2,0)
            int s2 = sa + 2; if (s2 >= 3) s2 -= 3;
            if (L2v)      stageA(rowOff[2], ks, s2);
            else if (L1)  stageA(rowOff[0], kn, s2);
            else          stageA(rowOff[0], kc2, s2);
            stageB(kc2, sb2);
            asm volatile("s_waitcnt vmcnt(12)" ::: "memory");
            asm volatile("s_barrier" ::: "memory");
            compute(acc[0], sa, sb);
            asm volatile("s_waitcnt lgkmcnt(0)" ::: "memory");
            asm volatile("s_barrier" ::: "memory");
            ++sa; if (sa == 3) sa = 0;
        }
        if (L1) {   // body (ks,1): next2 = L3v?(ks,3) : L2v?(ks+1,0) : (ks+1,1)
            int s2 = sa + 2; if (s2 >= 3) s2 -= 3;
            if (L3v)      stageA(rowOff[3], ks, s2);
            else if (L2v) stageA(rowOff[0], kn, s2);
            else          stageA(rowOff[1], kn, s2);
            stageB(kc2, sb2);
            asm volatile("s_waitcnt vmcnt(12)" ::: "memory");
            asm volatile("s_barrier" ::: "memory");
            compute(acc[1], sa, sb);
            asm volatile("s_waitcnt lgkmcnt(0)" ::: "memory");
            asm volatile("s_barrier" ::: "memory");
            ++sa; if (sa == 3) sa = 0;
        }
        if (L2v) {  // body (ks,2): next2 = L3v?(ks+1,0) : (ks+1,1)
            int s2 = sa + 2; if (s2 >= 3) s2 -= 3;
            if (L3v) stageA(rowOff[0], kn, s2);
            else     stageA(rowOff[1], kn, s2);
            stageB(kc2, sb2);
            asm volatile("s_waitcnt vmcnt(12)" ::: "memory");
            asm volatile("s_barrier" ::: "memory");
            compute(acc[2], sa, sb);
            asm volatile("s_waitcnt lgkmcnt(0)" ::: "memory");
            asm volatile("s_barrier" ::: "memory");
            ++sa; if (sa == 3) sa = 0;
        }
        if (L3v) {  // body (ks,3): next2 = (ks+1,1)
            int s2 = sa + 2; if (s2 >= 3) s2 -= 3;
            stageA(rowOff[1], kn, s2);
            stageB(kc2, sb2);
            asm volatile("s_waitcnt vmcnt(12)" ::: "memory");
            asm volatile("s_barrier" ::: "memory");
            compute(acc[3], sa, sb);
            asm volatile("s_waitcnt lgkmcnt(0)" ::: "memory");
            asm volatile("s_barrier" ::: "memory");
            ++sa; if (sa == 3) sa = 0;
        }
        ++sb; if (sb == 3) sb = 0;
    }
    asm volatile("s_waitcnt vmcnt(0)" ::: "memory");        // drain phantoms

    #pragma unroll
    for (int mt = 0; mt < 4; ++mt) {
        if (mt * 128 < cnt) {
            #pragma unroll
            for (int j = 0; j < 2; ++j) {
                const int n = n0 + wc * 32 + j * 16 + (lane & 15);
                const float bias = b1[t * Dn + n];
                #pragma unroll
                for (int i = 0; i < 4; ++i) {
                    #pragma unroll
                    for (int r = 0; r < 4; ++r) {
                        const int row = wr * 64 + i * 16 + (lane >> 4) * 4 + r;
                        if (mt * 128 + row < cnt) {
                            float v = acc[mt][i][j][r] + bias;
                            v = v > 0.f ? v : 0.f;
                            hbuf[(size_t)(t * CAP + mt * 128 + row) * Dn + n] = f2b(v);
                        }
                    }
                }
            }
        }
    }
}

// ---------------- gemm2 fused-K + epilogue (tanh, std, scatter) --------------
__global__ __launch_bounds__(256, 3) void k_gemm2(
    const u16* __restrict__ hbuf, const float* __restrict__ w2,
    const float* __restrict__ b2, const float* __restrict__ sigma,
    const int* __restrict__ cursor, const int* __restrict__ bucket,
    float* __restrict__ out) {
    __shared__ __align__(16) u16 Asl[32 * 256];   // 16KB [row][k] swizzled
    __shared__ __align__(16) u16 Bsl[64 * 256];   // 32KB [a][k]  swizzled

    const int bid = blockIdx.x;
    const int t = bid & 15, mt = bid >> 4;        // mt 0..15 (32-row tiles)
    int cnt = cursor[t]; if (cnt > CAP) cnt = CAP;
    const int m0 = mt * 32;
    if (m0 >= cnt) return;
    const int tid = threadIdx.x, lane = tid & 63, wv = tid >> 6;
    const int rh = wv & 1, ag = wv >> 1;

    f32x4 acc[2] = {};
    for (int c = 0; c < 4; ++c) {
        const int k0 = c * 256;
        #pragma unroll
        for (int i = 0; i < 4; ++i) {
            int chunk = i * 256 + tid;
            int row = chunk >> 5, cp = chunk & 31;
            int rowg = m0 + row; if (rowg >= cnt) rowg = cnt - 1;
            gload_lds16(hbuf + (size_t)(t * CAP + rowg) * Dn + k0 + 8 * (cp ^ (row & 7)),
                        &Asl[chunk * 8]);
        }
        {
            const int a = tid & 63, kcq = tid >> 6;
            const float* gB = w2 + ((size_t)t * Dn + k0 + kcq * 64) * An + a;
            for (int jb = 0; jb < 8; ++jb) {
                float v[8];
                #pragma unroll
                for (int u = 0; u < 8; ++u) v[u] = gB[(size_t)(jb * 8 + u) * An];
                int k = kcq * 64 + jb * 8;
                uint4 w = {pk2(v[0], v[1]), pk2(v[2], v[3]), pk2(v[4], v[5]), pk2(v[6], v[7])};
                *(uint4*)&Bsl[a * 256 + 8 * ((k >> 3) ^ (a & 7))] = w;
            }
        }
        __syncthreads();
        #pragma unroll
        for (int s = 0; s < 8; ++s) {
            const int r = lane & 15, ch = lane >> 4, cp = s * 4 + ch;
            const int row = rh * 16 + r;
            bf16x8 af = *(const bf16x8*)&Asl[row * 256 + 8 * (cp ^ (row & 7))];
            #pragma unroll
            for (int j = 0; j < 2; ++j) {
                const int a = ag * 32 + j * 16 + r;
                bf16x8 bf = *(const bf16x8*)&Bsl[a * 256 + 8 * (cp ^ (a & 7))];
                acc[j] = __builtin_amdgcn_mfma_f32_16x16x32_bf16(af, bf, acc[j], 0, 0, 0);
            }
        }
        __syncthreads();
    }

    #pragma unroll
    for (int j = 0; j < 2; ++j) {
        const int a = ag * 32 + j * 16 + (lane & 15);
        const float bias = b2[t * An + a];
        const float sd = expf(sigma[t * An + a]);
        #pragma unroll
        for (int r = 0; r < 4; ++r) {
            const int row = m0 + rh * 16 + (lane >> 4) * 4 + r;
            if (row < cnt) {
                const int orig = bucket[t * CAP + row];
                out[(size_t)orig * An + a] = tanhf(acc[j][r] + bias);
                out[(size_t)Bn * An + (size_t)orig * An + a] = sd;
            }
        }
    }
}

// ---------------- launch: 4 nodes, no memset ----------------
extern "C" void kernel_launch(void* const* d_in, const int* in_sizes, int n_in,
                              void* d_out, int out_size, void* d_ws, size_t ws_size,
                              hipStream_t stream) {
    const float* feature = (const float*)d_in[0];
    const float* actor_index = (const float*)d_in[1];
    const float* W1 = (const float*)d_in[2];
    const float* b1 = (const float*)d_in[3];
    const float* W2 = (const float*)d_in[4];
    const float* b2 = (const float*)d_in[5];
    const float* sigma = (const float*)d_in[6];
    float* out = (float*)d_out;
    char* ws = (char*)d_ws;

    if (ws_size < WS_NEED) return;

    int* cursor = (int*)(ws + OFF_CURSOR);
    int* bucket = (int*)(ws + OFF_BUCKET);
    u16* featb  = (u16*)(ws + OFF_FEATB);
    u16* w1t    = (u16*)(ws + OFF_W1T);
    u16* hbuf   = (u16*)(ws + OFF_H);

    k_prep<<<5120, 256, 0, stream>>>(feature, W1, featb, w1t, cursor, bucket);
    k_scatter<<<Bn / 256, 256, 0, stream>>>(actor_index, cursor, bucket);
    k_gemm1<<<Tn * 16, 256, 0, stream>>>(featb, w1t, b1, bucket, cursor, hbuf);
    k_gemm2<<<Tn * 16, 256, 0, stream>>>(hbuf, W2, b2, sigma, cursor, bucket, out);
}

// Round 9
// 72.194 us; speedup vs baseline: 1.3600x; 1.3600x over previous
//
#include <hip/hip_runtime.h>
#include <cmath>

#define DEVFN __device__ __forceinline__

constexpr int Bn = 4096, Dn = 1024, An = 64, Tn = 16;
constexpr int CAP = 336;     // per-task row capacity (mean 256, +5.2 sigma)

// ---------------- workspace layout (bytes) ----------------
constexpr size_t OFF_CURSOR  = 0;                                  // Tn ints (256B zone)
constexpr size_t OFF_BUCKET  = 256;                                // Tn*CAP ints
constexpr size_t OFF_ROWDEST = OFF_BUCKET + (size_t)4 * Tn * CAP;  // Bn ints
constexpr size_t OFF_FCOMP   = OFF_ROWDEST + (size_t)4 * Bn;       // bf16 [Tn*CAP][Dn]
constexpr size_t OFF_W1T     = OFF_FCOMP + (size_t)2 * Tn * CAP * Dn; // bf16 [Tn][n][k] 32MB
constexpr size_t OFF_H       = OFF_W1T + (size_t)2 * Tn * Dn * Dn;    // bf16 [Tn*CAP][Dn]
constexpr size_t WS_NEED     = OFF_H + (size_t)2 * Tn * CAP * Dn;     // ~55.6MB (<56.1 known OK)

typedef unsigned short u16;
typedef unsigned int uint32;
typedef __bf16 bf16x8 __attribute__((ext_vector_type(8)));
typedef float f32x4 __attribute__((ext_vector_type(4)));

DEVFN u16 f2b(float x) {            // f32 -> bf16 RNE
    unsigned u = __float_as_uint(x);
    u = u + 0x7FFFu + ((u >> 16) & 1u);
    return (u16)(u >> 16);
}
DEVFN uint32 pk2(float lo, float hi) {   // packed f32x2 -> bf16x2 (RNE)
    uint32 r;
    asm("v_cvt_pk_bf16_f32 %0, %1, %2" : "=v"(r) : "v"(lo), "v"(hi));
    return r;
}
DEVFN void gload_lds16(const void* g, void* l) {
    __builtin_amdgcn_global_load_lds(
        (const __attribute__((address_space(1))) void*)g,
        (__attribute__((address_space(3))) void*)l, 16, 0, 0);
}

// ---------------- scatter (runs FIRST): argmax + bucket + inverse map --------
__global__ void k_scatter(const float* __restrict__ ai, int* __restrict__ cursor,
                          int* __restrict__ bucket, int* __restrict__ rowdest) {
    int b = blockIdx.x * 256 + threadIdx.x;
    if (b >= Bn) return;
    const float4* r = (const float4*)(ai + (size_t)b * Tn);
    float4 v0 = r[0], v1 = r[1], v2 = r[2], v3 = r[3];
    float vals[16] = {v0.x, v0.y, v0.z, v0.w, v1.x, v1.y, v1.z, v1.w,
                      v2.x, v2.y, v2.z, v2.w, v3.x, v3.y, v3.z, v3.w};
    float best = vals[0]; int bi = 0;
    #pragma unroll
    for (int i = 1; i < Tn; ++i) if (vals[i] > best) { best = vals[i]; bi = i; }
    int pos = atomicAdd(&cursor[bi], 1);
    int dst = bi * CAP;                 // overflow fallback (P ~ 2e-6): slot 0
    if (pos < CAP) { bucket[bi * CAP + pos] = b; dst = bi * CAP + pos; }
    rowdest[b] = dst;
}

// ------- prep: feature cvt -> COMPACTED rows + W1 transpose-cvt (verified) ---
// Feature rows land at rowdest[b] (row-granular permutation; 2KB rows keep the
// write fully coalesced) -> gemm1's A staging becomes DENSE/contiguous. This
// removes the per-lane 2KB-strided gather (64 scattered 16B transactions per
// gload_lds) that was present in EVERY 39-55us gemm1 variant (r0-r8) -- the
// suspected invariant wall after demand-bytes (r8: FETCH 20.6MB, still 54us)
// and schedule/occupancy (r1-r7) were falsified.
__global__ __launch_bounds__(256) void k_prep(
    const float* __restrict__ feat, const float* __restrict__ w1,
    const int* __restrict__ rowdest, u16* __restrict__ fcomp, u16* __restrict__ w1t) {
    __shared__ float tile[64][65];
    const int bid = blockIdx.x, tid = threadIdx.x;
    if (bid < 1024) {
        const float4* s = (const float4*)feat;
        ushort4* d = (ushort4*)fcomp;
        #pragma unroll
        for (int i = 0; i < 4; ++i) {
            const int r = bid * 4 + i;
            const int dest = rowdest[r];                    // uniform -> s_load
            float4 v = s[(size_t)r * 256 + tid];
            ushort4 o = {f2b(v.x), f2b(v.y), f2b(v.z), f2b(v.w)};
            d[(size_t)dest * 256 + tid] = o;
        }
    } else {
        const int tb = bid - 1024;            // 0..4095
        const int t = tb >> 8;
        const int rest = tb & 255;
        const int k0 = (rest & 15) * 64, n0 = (rest >> 4) * 64;
        const float* s = w1 + ((size_t)t * Dn + k0) * Dn + n0;
        #pragma unroll
        for (int i = 0; i < 4; ++i) {
            const int row = i * 16 + (tid >> 4);
            const int c = (tid & 15) * 4;
            float4 v = *(const float4*)&s[(size_t)row * Dn + c];
            tile[row][c] = v.x; tile[row][c + 1] = v.y;
            tile[row][c + 2] = v.z; tile[row][c + 3] = v.w;
        }
        __syncthreads();
        u16* d = w1t + ((size_t)t * Dn + n0) * Dn + k0;
        #pragma unroll
        for (int i = 0; i < 2; ++i) {
            const int chunk = i * 256 + tid;
            const int nr = chunk >> 3, kc = chunk & 7;
            float v[8];
            #pragma unroll
            for (int u = 0; u < 8; ++u) v[u] = tile[kc * 8 + u][nr];
            uint4 w = {pk2(v[0], v[1]), pk2(v[2], v[3]), pk2(v[4], v[5]), pk2(v[6], v[7])};
            *(uint4*)&d[(size_t)nr * Dn + kc * 8] = w;
        }
    }
}

// ---------------- gemm1: DENSE h = relu(fcomp @ W1T[t] + b1[t]) --------------
// r0's session-verified structure VERBATIM (BM=128, BN=128, BK=64, 512 thr =
// 8 waves of 64x32, 64KB LDS -> 2 blk/CU, distance-1 counted schedule:
//   {stage(k+1); vmcnt(4); barrier; compute(k); barrier}
// vmcnt(4) retires exactly tile k's 4 gload_lds; tile k+1 rides through), with
// ONE change: the ri[]/bucket gather is gone -- A rows are dense/contiguous in
// fcomp, so every gload_lds is 8x coalesced 128B transactions. Single-variable
// experiment for the gather-wall theory.
__global__ __launch_bounds__(512, 4) void k_gemm1(
    const u16* __restrict__ fcomp, const u16* __restrict__ w1t,
    const float* __restrict__ b1, const int* __restrict__ cursor,
    u16* __restrict__ hbuf) {
    __shared__ __align__(16) u16 As[2][128 * 64];   // 16KB x2
    __shared__ __align__(16) u16 Bs[2][128 * 64];   // 16KB x2  (64KB total)

    const int bid = blockIdx.x;                     // t fastest -> XCD pin
    const int t = bid & 15, nt = (bid >> 4) & 7, mt = bid >> 7;   // mt 0..2
    int cnt = cursor[t]; if (cnt > CAP) cnt = CAP;
    const int m0 = mt * 128;
    if (m0 >= cnt) return;
    const int n0 = nt * 128;
    const int tid = threadIdx.x, lane = tid & 63, wv = tid >> 6;
    const int wr = wv >> 2, wc = wv & 3;            // 2 x 4 wave grid, tile 64x32

    // staging: chunk g = i*512+tid -> row g>>3 (0..127), k-slot g&7;
    // linear LDS dest + inverse-swizzled source (rule #21). 4 gload_lds/thread.
    const int kc = tid & 7, r8 = tid >> 3;          // r8: 0..63
    const u16* wbase = w1t + ((size_t)t * Dn + n0) * Dn;
    const u16* pa[2]; const u16* pb[2];
    #pragma unroll
    for (int i = 0; i < 2; ++i) {
        const int row = i * 64 + r8;
        pa[i] = fcomp + (size_t)(t * CAP + m0 + row) * Dn + 8 * (kc ^ (row & 7));
        pb[i] = wbase + (size_t)row * Dn + 8 * (kc ^ (row & 7));
    }

    // exactly 4 gload_lds per stage -> vmcnt(4) arithmetic below
    auto stage = [&](int buf, int k0) {
        #pragma unroll
        for (int i = 0; i < 2; ++i)
            gload_lds16(pa[i] + k0, &As[buf][(i * 512 + tid) * 8]);
        #pragma unroll
        for (int i = 0; i < 2; ++i)
            gload_lds16(pb[i] + k0, &Bs[buf][(i * 512 + tid) * 8]);
    };

    f32x4 acc[4][2] = {};
    asm volatile("s_waitcnt vmcnt(0)" ::: "memory");    // clean queue baseline
    stage(0, 0);
    for (int ks = 0; ks < 16; ++ks) {
        const int cur = ks & 1;
        if (ks < 15) {
            stage(cur ^ 1, (ks + 1) * 64);
            asm volatile("s_waitcnt vmcnt(4)\n\ts_barrier" ::: "memory");
        } else {
            asm volatile("s_waitcnt vmcnt(0)\n\ts_barrier" ::: "memory");
        }
        #pragma unroll
        for (int h = 0; h < 2; ++h) {
            const int kq = h * 4 + (lane >> 4);
            bf16x8 af[4], bfr[2];
            #pragma unroll
            for (int i = 0; i < 4; ++i) {
                int rr = wr * 64 + i * 16 + (lane & 15);
                af[i] = *(const bf16x8*)&As[cur][rr * 64 + 8 * (kq ^ (rr & 7))];
            }
            #pragma unroll
            for (int j = 0; j < 2; ++j) {
                int nn = wc * 32 + j * 16 + (lane & 15);
                bfr[j] = *(const bf16x8*)&Bs[cur][nn * 64 + 8 * (kq ^ (nn & 7))];
            }
            #pragma unroll
            for (int i = 0; i < 4; ++i)
                #pragma unroll
                for (int j = 0; j < 2; ++j)
                    acc[i][j] = __builtin_amdgcn_mfma_f32_16x16x32_bf16(af[i], bfr[j], acc[i][j], 0, 0, 0);
        }
        // bare barrier: NO vmcnt drain (tile ks+1 stays in flight); protects
        // buf(cur) from next iteration's staging DMA (compiler-emitted lgkm
        // waits before the MFMAs retired all LDS reads of cur).
        asm volatile("s_barrier" ::: "memory");
    }

    #pragma unroll
    for (int j = 0; j < 2; ++j) {
        const int n = n0 + wc * 32 + j * 16 + (lane & 15);
        const float bias = b1[t * Dn + n];
        #pragma unroll
        for (int i = 0; i < 4; ++i) {
            #pragma unroll
            for (int r = 0; r < 4; ++r) {
                const int row = wr * 64 + i * 16 + (lane >> 4) * 4 + r;
                if (m0 + row < cnt) {
                    float v = acc[i][j][r] + bias;
                    v = v > 0.f ? v : 0.f;
                    hbuf[(size_t)(t * CAP + m0 + row) * Dn + n] = f2b(v);
                }
            }
        }
    }
}

// ---------------- gemm2 fused-K + epilogue (tanh, std, scatter) --------------
__global__ __launch_bounds__(256, 3) void k_gemm2(
    const u16* __restrict__ hbuf, const float* __restrict__ w2,
    const float* __restrict__ b2, const float* __restrict__ sigma,
    const int* __restrict__ cursor, const int* __restrict__ bucket,
    float* __restrict__ out) {
    __shared__ __align__(16) u16 Asl[32 * 256];   // 16KB [row][k] swizzled
    __shared__ __align__(16) u16 Bsl[64 * 256];   // 32KB [a][k]  swizzled

    const int bid = blockIdx.x;
    const int t = bid & 15, mt = bid >> 4;        // mt 0..10 (32-row tiles)
    int cnt = cursor[t]; if (cnt > CAP) cnt = CAP;
    const int m0 = mt * 32;
    if (m0 >= cnt) return;
    const int tid = threadIdx.x, lane = tid & 63, wv = tid >> 6;
    const int rh = wv & 1, ag = wv >> 1;

    f32x4 acc[2] = {};
    for (int c = 0; c < 4; ++c) {
        const int k0 = c * 256;
        #pragma unroll
        for (int i = 0; i < 4; ++i) {
            int chunk = i * 256 + tid;
            int row = chunk >> 5, cp = chunk & 31;
            int rowg = m0 + row; if (rowg >= cnt) rowg = cnt - 1;
            gload_lds16(hbuf + (size_t)(t * CAP + rowg) * Dn + k0 + 8 * (cp ^ (row & 7)),
                        &Asl[chunk * 8]);
        }
        {
            const int a = tid & 63, kcq = tid >> 6;
            const float* gB = w2 + ((size_t)t * Dn + k0 + kcq * 64) * An + a;
            for (int jb = 0; jb < 8; ++jb) {
                float v[8];
                #pragma unroll
                for (int u = 0; u < 8; ++u) v[u] = gB[(size_t)(jb * 8 + u) * An];
                int k = kcq * 64 + jb * 8;
                uint4 w = {pk2(v[0], v[1]), pk2(v[2], v[3]), pk2(v[4], v[5]), pk2(v[6], v[7])};
                *(uint4*)&Bsl[a * 256 + 8 * ((k >> 3) ^ (a & 7))] = w;
            }
        }
        __syncthreads();
        #pragma unroll
        for (int s = 0; s < 8; ++s) {
            const int r = lane & 15, ch = lane >> 4, cp = s * 4 + ch;
            const int row = rh * 16 + r;
            bf16x8 af = *(const bf16x8*)&Asl[row * 256 + 8 * (cp ^ (row & 7))];
            #pragma unroll
            for (int j = 0; j < 2; ++j) {
                const int a = ag * 32 + j * 16 + r;
                bf16x8 bf = *(const bf16x8*)&Bsl[a * 256 + 8 * (cp ^ (a & 7))];
                acc[j] = __builtin_amdgcn_mfma_f32_16x16x32_bf16(af, bf, acc[j], 0, 0, 0);
            }
        }
        __syncthreads();
    }

    #pragma unroll
    for (int j = 0; j < 2; ++j) {
        const int a = ag * 32 + j * 16 + (lane & 15);
        const float bias = b2[t * An + a];
        const float sd = expf(sigma[t * An + a]);
        #pragma unroll
        for (int r = 0; r < 4; ++r) {
            const int row = m0 + rh * 16 + (lane >> 4) * 4 + r;
            if (row < cnt) {
                const int orig = bucket[t * CAP + row];
                out[(size_t)orig * An + a] = tanhf(acc[j][r] + bias);
                out[(size_t)Bn * An + (size_t)orig * An + a] = sd;
            }
        }
    }
}

// ---------------- launch: memset(cursor) + 4 kernels ----------------
extern "C" void kernel_launch(void* const* d_in, const int* in_sizes, int n_in,
                              void* d_out, int out_size, void* d_ws, size_t ws_size,
                              hipStream_t stream) {
    const float* feature = (const float*)d_in[0];
    const float* actor_index = (const float*)d_in[1];
    const float* W1 = (const float*)d_in[2];
    const float* b1 = (const float*)d_in[3];
    const float* W2 = (const float*)d_in[4];
    const float* b2 = (const float*)d_in[5];
    const float* sigma = (const float*)d_in[6];
    float* out = (float*)d_out;
    char* ws = (char*)d_ws;

    if (ws_size < WS_NEED) return;

    int* cursor  = (int*)(ws + OFF_CURSOR);
    int* bucket  = (int*)(ws + OFF_BUCKET);
    int* rowdest = (int*)(ws + OFF_ROWDEST);
    u16* fcomp   = (u16*)(ws + OFF_FCOMP);
    u16* w1t     = (u16*)(ws + OFF_W1T);
    u16* hbuf    = (u16*)(ws + OFF_H);

    hipMemsetAsync(cursor, 0, 256, stream);
    k_scatter<<<Bn / 256, 256, 0, stream>>>(actor_index, cursor, bucket, rowdest);
    k_prep<<<5120, 256, 0, stream>>>(feature, W1, rowdest, fcomp, w1t);
    k_gemm1<<<Tn * 8 * 3, 512, 0, stream>>>(fcomp, w1t, b1, cursor, hbuf);
    k_gemm2<<<Tn * 11, 256, 0, stream>>>(hbuf, W2, b2, sigma, cursor, bucket, out);
}